// Round 1
// baseline (300.639 us; speedup 1.0000x reference)
//
#include <hip/hip_runtime.h>
#include <stdint.h>

typedef unsigned short u16;
typedef __attribute__((ext_vector_type(8))) __bf16 bf16x8;
typedef __attribute__((ext_vector_type(4))) float f32x4;

__device__ __forceinline__ u16 f2bf(float f) {
    union { float f; uint32_t u; } v; v.f = f;
    uint32_t r = (v.u + 0x7FFFu + ((v.u >> 16) & 1u)) >> 16;
    return (u16)r;
}
__device__ __forceinline__ float bf2f(u16 u) {
    union { uint32_t u; float f; } v; v.u = ((uint32_t)u) << 16;
    return v.f;
}

#define BM 128
#define BN 128
#define BK 32

// C = A * Bt^T where A is [M,K] bf16 row-major, Bt is [N,K] bf16 row-major.
// MODE 0: bf16 out + bias           (q/k projection)
// MODE 1: bf16 out + bias, write transposed as [b, n, s] with gm=b*2048+s (v proj)
// MODE 2: bf16 out * scale          (scores)
// MODE 3: fp32 out                  (final attn @ v)
template<int MODE>
__global__ __launch_bounds__(256, 2) void gemm_bt(
    const u16* __restrict__ A, const u16* __restrict__ Bt,
    const float* __restrict__ bias, void* __restrict__ Cout,
    int M, int N, int K,
    long sA, long sB, long sC, float scale)
{
    __shared__ __align__(16) u16 As[BM * BK];
    __shared__ __align__(16) u16 Bs[BN * BK];
    const int t = threadIdx.x;
    const int lane = t & 63;
    const int wave = t >> 6;
    const int wm = (wave & 1) * 64;
    const int wn = (wave >> 1) * 64;
    const int bm = blockIdx.y * BM;
    const int bn = blockIdx.x * BN;
    const long bz = blockIdx.z;
    const u16* Ab = A + bz * sA;
    const u16* Bb = Bt + bz * sB;

    f32x4 acc[4][4];
#pragma unroll
    for (int i = 0; i < 4; ++i)
#pragma unroll
        for (int j = 0; j < 4; ++j)
            acc[i][j] = (f32x4){0.f, 0.f, 0.f, 0.f};

    const int lrow = t >> 2;          // 0..63
    const int lcol = (t & 3) * 8;     // 0,8,16,24

    for (int k0 = 0; k0 < K; k0 += BK) {
        // Stage A tile: 128x32 bf16, 16B per thread per issue, LDS row-major [128][32]
#pragma unroll
        for (int r = 0; r < 2; ++r) {
            const u16* ga = Ab + (long)(bm + r * 64 + lrow) * K + (k0 + lcol);
            __builtin_amdgcn_global_load_lds(
                (const __attribute__((address_space(1))) void*)ga,
                (__attribute__((address_space(3))) void*)&As[(r * 256 + t) * 8],
                16, 0, 0);
        }
#pragma unroll
        for (int r = 0; r < 2; ++r) {
            const u16* gb = Bb + (long)(bn + r * 64 + lrow) * K + (k0 + lcol);
            __builtin_amdgcn_global_load_lds(
                (const __attribute__((address_space(1))) void*)gb,
                (__attribute__((address_space(3))) void*)&Bs[(r * 256 + t) * 8],
                16, 0, 0);
        }
        __syncthreads();

        const int fm = lane & 15;
        const int fk = (lane >> 4) * 8;
        bf16x8 af[4], bfr[4];
#pragma unroll
        for (int i = 0; i < 4; ++i) {
            af[i]  = *(const bf16x8*)&As[(wm + i * 16 + fm) * BK + fk];
            bfr[i] = *(const bf16x8*)&Bs[(wn + i * 16 + fm) * BK + fk];
        }
#pragma unroll
        for (int i = 0; i < 4; ++i)
#pragma unroll
            for (int j = 0; j < 4; ++j)
                acc[i][j] = __builtin_amdgcn_mfma_f32_16x16x32_bf16(af[i], bfr[j], acc[i][j], 0, 0, 0);
        __syncthreads();
    }

    // Epilogue. C/D layout: col = lane&15, row = (lane>>4)*4 + reg  [m89/m91 verified]
    const int cm = (lane >> 4) * 4;
    const int cn = lane & 15;
#pragma unroll
    for (int i = 0; i < 4; ++i) {
#pragma unroll
        for (int j = 0; j < 4; ++j) {
            const int gn = bn + wn + j * 16 + cn;
            float bv = 0.f;
            if (MODE <= 1) bv = bias[gn];
#pragma unroll
            for (int r = 0; r < 4; ++r) {
                const int gm = bm + wm + i * 16 + cm + r;
                const float val = acc[i][j][r];
                if (MODE == 0) {
                    ((u16*)Cout)[bz * sC + (long)gm * N + gn] = f2bf(val + bv);
                } else if (MODE == 1) {
                    const int b = gm >> 11, s = gm & 2047;
                    ((u16*)Cout)[(((long)b * 1024 + gn) << 11) + s] = f2bf(val + bv);
                } else if (MODE == 2) {
                    ((u16*)Cout)[bz * sC + (long)gm * N + gn] = f2bf(val * scale);
                } else {
                    ((float*)Cout)[bz * sC + (long)gm * N + gn] = val;
                }
            }
        }
    }
}

__global__ void cvt_f32_bf16(const float* __restrict__ in, u16* __restrict__ out, int n) {
    const int i = (blockIdx.x * blockDim.x + threadIdx.x) * 4;
    if (i >= n) return;
    f32x4 f = *(const f32x4*)(in + i);
    uint2 o;
    o.x = (uint32_t)f2bf(f[0]) | ((uint32_t)f2bf(f[1]) << 16);
    o.y = (uint32_t)f2bf(f[2]) | ((uint32_t)f2bf(f[3]) << 16);
    *(uint2*)(out + i) = o;
}

// One block per row, 256 threads, ncol = 2048 (8 elems/thread), in-place bf16.
__global__ __launch_bounds__(256) void softmax_rows(u16* __restrict__ S) {
    const long base = (long)blockIdx.x * 2048;
    const int t = threadIdx.x;
    const int lane = t & 63, wave = t >> 6;
    __shared__ float red[4];
    float v[8];
    float m = -3.0e38f;
#pragma unroll
    for (int i = 0; i < 8; ++i) {
        v[i] = bf2f(S[base + t + i * 256]);
        m = fmaxf(m, v[i]);
    }
#pragma unroll
    for (int off = 32; off > 0; off >>= 1) m = fmaxf(m, __shfl_down(m, off));
    if (lane == 0) red[wave] = m;
    __syncthreads();
    m = fmaxf(fmaxf(red[0], red[1]), fmaxf(red[2], red[3]));
    __syncthreads();
    float sum = 0.f;
#pragma unroll
    for (int i = 0; i < 8; ++i) { v[i] = __expf(v[i] - m); sum += v[i]; }
#pragma unroll
    for (int off = 32; off > 0; off >>= 1) sum += __shfl_down(sum, off);
    if (lane == 0) red[wave] = sum;
    __syncthreads();
    sum = red[0] + red[1] + red[2] + red[3];
    const float inv = 1.0f / sum;
#pragma unroll
    for (int i = 0; i < 8; ++i) S[base + t + i * 256] = f2bf(v[i] * inv);
}

extern "C" void kernel_launch(void* const* d_in, const int* in_sizes, int n_in,
                              void* d_out, int out_size, void* d_ws, size_t ws_size,
                              hipStream_t stream) {
    const float* x  = (const float*)d_in[0];
    const float* Wq = (const float*)d_in[1];
    const float* bq = (const float*)d_in[2];
    const float* Wk = (const float*)d_in[3];
    const float* bk = (const float*)d_in[4];
    const float* Wv = (const float*)d_in[5];
    const float* bv = (const float*)d_in[6];
    float* out = (float*)d_out;

    const int B = 4, S = 2048, D = 1024, E = 1024;
    const int M = B * S; // 8192

    u16* xb  = (u16*)d_ws;                       // [M,D]       16 MB
    u16* wqb = xb  + (size_t)M * D;              // [E,D]        2 MB
    u16* wkb = wqb + (size_t)E * D;
    u16* wvb = wkb + (size_t)E * D;
    u16* qb  = wvb + (size_t)E * D;              // [M,E]       16 MB
    u16* kb  = qb  + (size_t)M * E;              // [M,E]       16 MB
    u16* vbT = kb  + (size_t)M * E;              // [B,E,S]     16 MB
    u16* sb  = vbT + (size_t)M * E;              // [B,S,S]     32 MB
    // total ~102 MB

    cvt_f32_bf16<<<(M * D / 4 + 255) / 256, 256, 0, stream>>>(x, xb, M * D);
    cvt_f32_bf16<<<(E * D / 4 + 255) / 256, 256, 0, stream>>>(Wq, wqb, E * D);
    cvt_f32_bf16<<<(E * D / 4 + 255) / 256, 256, 0, stream>>>(Wk, wkb, E * D);
    cvt_f32_bf16<<<(E * D / 4 + 255) / 256, 256, 0, stream>>>(Wv, wvb, E * D);

    dim3 blk(256);
    // Q/K/V projections
    gemm_bt<0><<<dim3(E / BN, M / BM, 1), blk, 0, stream>>>(xb, wqb, bq, qb, M, E, D, 0, 0, 0, 1.f);
    gemm_bt<0><<<dim3(E / BN, M / BM, 1), blk, 0, stream>>>(xb, wkb, bk, kb, M, E, D, 0, 0, 0, 1.f);
    gemm_bt<1><<<dim3(E / BN, M / BM, 1), blk, 0, stream>>>(xb, wvb, bv, vbT, M, E, D, 0, 0, 0, 1.f);
    // scores = q @ k^T / 32, per batch
    gemm_bt<2><<<dim3(S / BN, S / BM, B), blk, 0, stream>>>(qb, kb, nullptr, sb, S, S, E,
        (long)S * E, (long)S * E, (long)S * S, 0.03125f);
    // softmax rows (in place, bf16)
    softmax_rows<<<M, 256, 0, stream>>>(sb);
    // out = attn @ v  (vbT is [E,S] per batch = B^T form)
    gemm_bt<3><<<dim3(E / BN, S / BM, B), blk, 0, stream>>>(sb, vbT, nullptr, out, S, E, S,
        (long)S * S, (long)E * S, (long)S * E, 1.f);
}

// Round 2
// 273.108 us; speedup vs baseline: 1.1008x; 1.1008x over previous
//
#include <hip/hip_runtime.h>
#include <stdint.h>

typedef unsigned short u16;
typedef __attribute__((ext_vector_type(8))) __bf16 bf16x8;
typedef __attribute__((ext_vector_type(4))) float f32x4;

__device__ __forceinline__ u16 f2bf(float f) {
    union { float f; uint32_t u; } v; v.f = f;
    uint32_t r = (v.u + 0x7FFFu + ((v.u >> 16) & 1u)) >> 16;
    return (u16)r;
}
__device__ __forceinline__ float bf2f(u16 u) {
    union { uint32_t u; float f; } v; v.u = ((uint32_t)u) << 16;
    return v.f;
}

#define BM 128
#define BN 128
#define BK 32

// C = A * Bt^T, A [M,K] bf16 rm, Bt [N,K] bf16 rm.
// MODE 0: fused QKV projection. N=3072. Section by bn>>10: 0->q (bias b0, out o0),
//         1->k (b1, o1), 2->v bias b2 written TRANSPOSED as [b,e,s] into o2.
// MODE 2: bf16 out * scale into o0 (scores)
// MODE 3: fp32 out into o3 (attn @ v)
template<int MODE>
__global__ __launch_bounds__(256, 2) void gemm_bt(
    const u16* __restrict__ A, const u16* __restrict__ Bt,
    const float* __restrict__ b0, const float* __restrict__ b1, const float* __restrict__ b2,
    u16* __restrict__ o0, u16* __restrict__ o1, u16* __restrict__ o2,
    float* __restrict__ o3,
    int M, int N, int K, long sA, long sB, long sC, float scale)
{
    __shared__ __align__(16) u16 smem[BM * BK + BN * BK]; // 16 KB
    u16* As = smem;
    u16* Bs = smem + BM * BK;
    u16* Es = smem; // epilogue reuse (max 32*144=4608 or 128*40=5120 u16)

    const int t = threadIdx.x;
    const int lane = t & 63;
    const int wave = t >> 6;
    const int wm = (wave & 1) * 64;
    const int wn = (wave >> 1) * 64;
    const int bm = blockIdx.y * BM;
    const int bn = blockIdx.x * BN;
    const long bz = blockIdx.z;
    const u16* Ab = A + bz * sA;
    const u16* Bb = Bt + bz * sB;

    f32x4 acc[4][4];
#pragma unroll
    for (int i = 0; i < 4; ++i)
#pragma unroll
        for (int j = 0; j < 4; ++j)
            acc[i][j] = (f32x4){0.f, 0.f, 0.f, 0.f};

    const int lrow = t >> 2;
    const int lcol = (t & 3) * 8;

    for (int k0 = 0; k0 < K; k0 += BK) {
#pragma unroll
        for (int r = 0; r < 2; ++r) {
            const u16* ga = Ab + (long)(bm + r * 64 + lrow) * K + (k0 + lcol);
            __builtin_amdgcn_global_load_lds(
                (const __attribute__((address_space(1))) void*)ga,
                (__attribute__((address_space(3))) void*)&As[(r * 256 + t) * 8],
                16, 0, 0);
        }
#pragma unroll
        for (int r = 0; r < 2; ++r) {
            const u16* gb = Bb + (long)(bn + r * 64 + lrow) * K + (k0 + lcol);
            __builtin_amdgcn_global_load_lds(
                (const __attribute__((address_space(1))) void*)gb,
                (__attribute__((address_space(3))) void*)&Bs[(r * 256 + t) * 8],
                16, 0, 0);
        }
        __syncthreads();

        const int fm = lane & 15;
        const int fk = (lane >> 4) * 8;
        bf16x8 af[4], bfr[4];
#pragma unroll
        for (int i = 0; i < 4; ++i) {
            af[i]  = *(const bf16x8*)&As[(wm + i * 16 + fm) * BK + fk];
            bfr[i] = *(const bf16x8*)&Bs[(wn + i * 16 + fm) * BK + fk];
        }
#pragma unroll
        for (int i = 0; i < 4; ++i)
#pragma unroll
            for (int j = 0; j < 4; ++j)
                acc[i][j] = __builtin_amdgcn_mfma_f32_16x16x32_bf16(af[i], bfr[j], acc[i][j], 0, 0, 0);
        __syncthreads();
    }

    // C/D layout: col = lane&15, row = (lane>>4)*4 + reg
    const int cm = (lane >> 4) * 4;
    const int cn = lane & 15;
    const int lr0 = (wave & 1) * 16 + cm; // local row base within 32-row epilogue tile

    if (MODE == 3) {
        // direct fp32 stores (PV)
#pragma unroll
        for (int i = 0; i < 4; ++i)
#pragma unroll
            for (int j = 0; j < 4; ++j) {
                const int gn = bn + wn + j * 16 + cn;
#pragma unroll
                for (int r = 0; r < 4; ++r) {
                    const int gm = bm + wm + i * 16 + cm + r;
                    o3[bz * sC + (long)gm * N + gn] = acc[i][j][r];
                }
            }
    } else if (MODE == 0 && (bn >> 10) == 2) {
        // ---- v projection, transposed write [b, e, s] ----
        float bb[4];
#pragma unroll
        for (int j = 0; j < 4; ++j) bb[j] = b2[(bn & 1023) + wn + j * 16 + cn];
#pragma unroll
        for (int i = 0; i < 4; ++i) {
            if (i) __syncthreads();
#pragma unroll
            for (int j = 0; j < 4; ++j) {
                const int e = wn + j * 16 + cn;
                ushort4 pk;
                pk.x = f2bf(acc[i][j][0] + bb[j]);
                pk.y = f2bf(acc[i][j][1] + bb[j]);
                pk.z = f2bf(acc[i][j][2] + bb[j]);
                pk.w = f2bf(acc[i][j][3] + bb[j]);
                *(ushort4*)&Es[e * 40 + lr0] = pk; // [e][s_local], stride 40 u16 (80B, 16B-aligned rows)
            }
            __syncthreads();
#pragma unroll
            for (int p = 0; p < 2; ++p) {
                const int e = p * 64 + (t >> 2);
                const int s8 = (t & 3) * 8;
                const uint4 w = *(const uint4*)&Es[e * 40 + s8];
                const int gmb = bm + i * 16 + (s8 < 16 ? s8 : 48 + s8);
                const int b = gmb >> 11, s = gmb & 2047;
                const int eg = (bn & 1023) + e;
                *(uint4*)&o2[(((long)b << 10) + eg) * 2048 + s] = w;
            }
        }
    } else {
        // ---- row-major bf16 epilogue via LDS retile (q, k, scores) ----
        u16* C;
        int Nout, ncol0;
        long cbase;
        const float* bias;
        if (MODE == 2) {
            C = o0; Nout = N; ncol0 = bn; cbase = bz * sC; bias = nullptr;
        } else {
            const int sec = bn >> 10;
            C = sec ? o1 : o0; Nout = 1024; ncol0 = bn & 1023; cbase = 0;
            bias = sec ? b1 : b0;
        }
        float bb[4];
#pragma unroll
        for (int j = 0; j < 4; ++j)
            bb[j] = bias ? bias[ncol0 + wn + j * 16 + cn] : 0.f;
#pragma unroll
        for (int i = 0; i < 4; ++i) {
            if (i) __syncthreads();
#pragma unroll
            for (int j = 0; j < 4; ++j) {
                const int col = wn + j * 16 + cn;
#pragma unroll
                for (int r = 0; r < 4; ++r) {
                    float v = acc[i][j][r];
                    v = (MODE == 2) ? v * scale : v + bb[j];
                    Es[(lr0 + r) * 144 + col] = f2bf(v); // stride 144 u16 (288B): 16B-aligned, banks spread
                }
            }
            __syncthreads();
#pragma unroll
            for (int p = 0; p < 2; ++p) {
                const int lr = p * 16 + (t >> 4);
                const int c8 = (t & 15) * 8;
                const uint4 w = *(const uint4*)&Es[lr * 144 + c8];
                const int gm = bm + i * 16 + (lr < 16 ? lr : 48 + lr);
                *(uint4*)&C[cbase + (long)gm * Nout + ncol0 + c8] = w;
            }
        }
    }
}

// fp32 -> bf16 converts, all fused: blocks [0,8192) -> x, then 1024 each for Wq/Wk/Wv
__global__ __launch_bounds__(256) void cvt_all(
    const float* __restrict__ x, const float* __restrict__ wq,
    const float* __restrict__ wk, const float* __restrict__ wv,
    u16* __restrict__ xb, u16* __restrict__ wb)
{
    const int b = blockIdx.x;
    const float* src; u16* dst; long base;
    if (b < 8192)       { src = x;  dst = xb;            base = (long)b * 1024; }
    else if (b < 9216)  { src = wq; dst = wb;            base = (long)(b - 8192) * 1024; }
    else if (b < 10240) { src = wk; dst = wb + (1 << 20); base = (long)(b - 9216) * 1024; }
    else                { src = wv; dst = wb + (2 << 20); base = (long)(b - 10240) * 1024; }
    const long i = base + threadIdx.x * 4;
    const f32x4 f = *(const f32x4*)(src + i);
    ushort4 o;
    o.x = f2bf(f[0]); o.y = f2bf(f[1]); o.z = f2bf(f[2]); o.w = f2bf(f[3]);
    *(ushort4*)(dst + i) = o;
}

// One block per row, 256 threads, 2048 cols, in-place bf16 softmax.
__global__ __launch_bounds__(256) void softmax_rows(u16* __restrict__ S) {
    const long base = (long)blockIdx.x * 2048;
    const int t = threadIdx.x;
    const int lane = t & 63, wave = t >> 6;
    __shared__ float red[4];
    float v[8];
    float m = -3.0e38f;
#pragma unroll
    for (int i = 0; i < 8; ++i) {
        v[i] = bf2f(S[base + t + i * 256]);
        m = fmaxf(m, v[i]);
    }
#pragma unroll
    for (int off = 32; off > 0; off >>= 1) m = fmaxf(m, __shfl_down(m, off));
    if (lane == 0) red[wave] = m;
    __syncthreads();
    m = fmaxf(fmaxf(red[0], red[1]), fmaxf(red[2], red[3]));
    __syncthreads();
    float sum = 0.f;
#pragma unroll
    for (int i = 0; i < 8; ++i) { v[i] = __expf(v[i] - m); sum += v[i]; }
#pragma unroll
    for (int off = 32; off > 0; off >>= 1) sum += __shfl_down(sum, off);
    if (lane == 0) red[wave] = sum;
    __syncthreads();
    sum = red[0] + red[1] + red[2] + red[3];
    const float inv = 1.0f / sum;
#pragma unroll
    for (int i = 0; i < 8; ++i) S[base + t + i * 256] = f2bf(v[i] * inv);
}

extern "C" void kernel_launch(void* const* d_in, const int* in_sizes, int n_in,
                              void* d_out, int out_size, void* d_ws, size_t ws_size,
                              hipStream_t stream) {
    const float* x  = (const float*)d_in[0];
    const float* Wq = (const float*)d_in[1];
    const float* bq = (const float*)d_in[2];
    const float* Wk = (const float*)d_in[3];
    const float* bk = (const float*)d_in[4];
    const float* Wv = (const float*)d_in[5];
    const float* bv = (const float*)d_in[6];
    float* out = (float*)d_out;

    const int B = 4, S = 2048, D = 1024, E = 1024;
    const int M = B * S; // 8192

    u16* xb  = (u16*)d_ws;                       // [M,D]
    u16* wb  = xb  + (size_t)M * D;              // [3E,D] concat Wq,Wk,Wv
    u16* qb  = wb  + (size_t)3 * E * D;          // [M,E]
    u16* kb  = qb  + (size_t)M * E;              // [M,E]
    u16* vbT = kb  + (size_t)M * E;              // [B,E,S]
    u16* sb  = vbT + (size_t)M * E;              // [B,S,S]

    cvt_all<<<11264, 256, 0, stream>>>(x, Wq, Wk, Wv, xb, wb);

    dim3 blk(256);
    // fused QKV projection: [8192,1024] x [3072,1024]^T
    gemm_bt<0><<<dim3(3 * E / BN, M / BM, 1), blk, 0, stream>>>(
        xb, wb, bq, bk, bv, qb, kb, vbT, nullptr, M, 3 * E, D, 0, 0, 0, 1.f);
    // scores = q @ k^T / 32 per batch
    gemm_bt<2><<<dim3(S / BN, S / BM, B), blk, 0, stream>>>(
        qb, kb, nullptr, nullptr, nullptr, sb, nullptr, nullptr, nullptr,
        S, S, E, (long)S * E, (long)S * E, (long)S * S, 0.03125f);
    softmax_rows<<<M, 256, 0, stream>>>(sb);
    // out = attn @ v
    gemm_bt<3><<<dim3(E / BN, S / BM, B), blk, 0, stream>>>(
        sb, vbT, nullptr, nullptr, nullptr, nullptr, nullptr, nullptr, out,
        S, E, S, (long)S * S, (long)E * S, (long)S * E, 1.f);
}